// Round 10
// baseline (317.462 us; speedup 1.0000x reference)
//
#include <hip/hip_runtime.h>
#include <hip/hip_bf16.h>
#include <math.h>

// Problem constants
#define BB 256
#define TT 512
#define EE 128
#define HH 128
#define NC 4

typedef float f32x4 __attribute__((ext_vector_type(4)));

// Branch-free tanh: 1 - 2/(1+e^{2x}) with e^{2x} = exp2(2*log2e*x).
// Saturates exactly (+/-1); ~1e-6 rel error.
__device__ __forceinline__ float fast_tanh(float x) {
    float t = __builtin_amdgcn_exp2f(x * 2.885390081777927f);
    return 1.f - 2.f * __builtin_amdgcn_rcpf(1.f + t);
}

// Barrier draining ONLY lgkmcnt (LDS), not vmcnt: keeps the embedding-row
// global loads in flight across barriers (__syncthreads vmcnt(0)-drains
// them every step [m97 asm evidence]).
__device__ __forceinline__ void bar_lds() {
    asm volatile("s_waitcnt lgkmcnt(0)\n\ts_barrier" ::: "memory");
}

// ---------------------------------------------------------------------------
// FULLY-FUSED kernel: embedding + input projection + recurrence + MLP head.
//   h_t = tanh( W_ih @ emb[x[b,t]] + b_ih + b_hh + W_hh @ h_{t-1} )
// One block per batch element (256 blocks, 1/CU), 256 threads = 4 waves.
// Wave q owns K-slice [32q,32q+32); lane l accumulates outputs {l, l+64}:
//   partial_o = sum_{k in slice} Whh[o,k] h[k] + Wih[o,k] e_t[k]
// Cross-wave combine (the ONE barrier/step) sums 4 partials -> full matvec
// for BOTH terms at once; bias + tanh in the owning wave (wave-private h
// slice -> no second barrier).
// Embedding rows stream: global->regs issued 2 windows (16 steps) ahead,
// regs->LDS ping-pong ebuf at each window's ts=7 (ordered by the existing
// barrier; double-buffer kills WAR; zero extra barriers).
// x_proj math is exact fp32 (better than the old split-bf16 MFMA path).
// ---------------------------------------------------------------------------
__global__ __launch_bounds__(256, 1) void rnn_fused(
    const int* __restrict__ x, const float* __restrict__ emb,
    const float* __restrict__ Wih, const float* __restrict__ Whh,
    const float* __restrict__ bih, const float* __restrict__ bhh,
    const float* __restrict__ h0, const float* __restrict__ W1,
    const float* __restrict__ b1, const float* __restrict__ W2,
    const float* __restrict__ b2, float* __restrict__ out)
{
    const int b    = blockIdx.x;
    const int tid  = threadIdx.x;
    const int q    = tid >> 6;       // wave id = K-slice = owned h slice
    const int lane = tid & 63;
    const int l32  = lane & 31;
    const bool owner = (lane < 32);
    const int o = q * 32 + l32;      // owned output element (owner lanes)

    __shared__ float h_priv[4][32];     // wave-private h slices
    __shared__ float part[2][4][128];   // ping-pong partials
    __shared__ float ebuf[2][8][128];   // ping-pong embedding-row windows
    __shared__ int   sx[TT];            // this block's token ids
    __shared__ float h_full[128];
    __shared__ float hid[256];

    // Stage token ids (512 ints, 2 per thread).
    {
        int2 v = ((const int2*)(x + (size_t)b * TT))[tid];
        *(int2*)&sx[tid * 2] = v;
    }

    // Weights in registers: rows o=lane and o=lane+64, K-slice [32q,32q+32).
    f32x4 wA[8], wB[8], iA[8], iB[8];
    {
        const float* hr0 = Whh + (size_t)lane * 128 + q * 32;
        const float* hr1 = Whh + (size_t)(lane + 64) * 128 + q * 32;
        const float* ir0 = Wih + (size_t)lane * 128 + q * 32;
        const float* ir1 = Wih + (size_t)(lane + 64) * 128 + q * 32;
#pragma unroll
        for (int c = 0; c < 8; ++c) {
            wA[c] = *(const f32x4*)(hr0 + c * 4);
            wB[c] = *(const f32x4*)(hr1 + c * 4);
            iA[c] = *(const f32x4*)(ir0 + c * 4);
            iB[c] = *(const f32x4*)(ir1 + c * 4);
        }
    }
#pragma unroll
    for (int c = 0; c < 8; ++c)
        asm volatile("" : "+v"(wA[c]), "+v"(wB[c]));
#pragma unroll
    for (int c = 0; c < 8; ++c)
        asm volatile("" : "+v"(iA[c]), "+v"(iB[c]));

    float bs_o = 0.f;
    if (owner) {
        bs_o = bih[o] + bhh[o];
        h_priv[q][l32] = h0[b * 128 + o];
    }
    __syncthreads();   // sx + h_priv visible

    // Prologue: window 0 (steps 0..7) direct to ebuf[0]; window 1 into regs.
    f32x4 eh0 = f32x4{0.f, 0.f, 0.f, 0.f}, eh1 = eh0;
    if (owner) {
        f32x4 e0a = *(const f32x4*)(emb + (size_t)sx[q]      * 128 + l32 * 4);
        f32x4 e0b = *(const f32x4*)(emb + (size_t)sx[q + 4]  * 128 + l32 * 4);
        eh0       = *(const f32x4*)(emb + (size_t)sx[q + 8]  * 128 + l32 * 4);
        eh1       = *(const f32x4*)(emb + (size_t)sx[q + 12] * 128 + l32 * 4);
        *(f32x4*)&ebuf[0][q][l32 * 4]     = e0a;
        *(f32x4*)&ebuf[0][q + 4][l32 * 4] = e0b;
    }
    bar_lds();   // ebuf[0] visible

    for (int tw = 0; tw < TT; tw += 8) {
        const int wb = (tw >> 3) & 1;
#pragma unroll
        for (int ts = 0; ts < 8; ++ts) {
            const int p = ts & 1;
            // ---- phase A: combined Whh-h + Wih-e dot over own slice ----
            const float* hq = &h_priv[q][0];
            const float* eq = &ebuf[wb][ts][q * 32];
            f32x4 aW = f32x4{0.f, 0.f, 0.f, 0.f};
            f32x4 bW = f32x4{0.f, 0.f, 0.f, 0.f};
            f32x4 aE = f32x4{0.f, 0.f, 0.f, 0.f};
            f32x4 bE = f32x4{0.f, 0.f, 0.f, 0.f};
#pragma unroll
            for (int u = 0; u < 8; ++u) {
                f32x4 h4 = *(const f32x4*)&hq[u * 4];
                f32x4 e4 = *(const f32x4*)&eq[u * 4];
                aW += wA[u] * h4;
                bW += wB[u] * h4;
                aE += iA[u] * e4;
                bE += iB[u] * e4;
            }
            f32x4 sA = aW + aE, sB = bW + bE;
            part[p][q][lane]      = (sA[0] + sA[1]) + (sA[2] + sA[3]);
            part[p][q][64 + lane] = (sB[0] + sB[1]) + (sB[2] + sB[3]);

            if (ts == 7) {
                // Stage window tw/8+1 regs -> ebuf[wb^1] (readers start only
                // after the barrier below; WAR dead since window tw/8-1's
                // readers are >=7 barriers behind).
                if (tw + 8 < TT && owner) {
                    *(f32x4*)&ebuf[wb ^ 1][q][l32 * 4]     = eh0;
                    *(f32x4*)&ebuf[wb ^ 1][q + 4][l32 * 4] = eh1;
                }
                // Issue window tw/8+2 global loads (16-step lookahead).
                if (tw + 16 < TT && owner) {
                    eh0 = *(const f32x4*)(emb + (size_t)sx[tw + 16 + q]     * 128 + l32 * 4);
                    eh1 = *(const f32x4*)(emb + (size_t)sx[tw + 16 + 4 + q] * 128 + l32 * 4);
                }
            }

            bar_lds();   // partials (+ staged ebuf at ts==7) visible

            // ---- phase B: combine + bias + tanh in the owning wave ----
            if (owner) {
                float s = (part[p][0][o] + part[p][1][o])
                        + (part[p][2][o] + part[p][3][o]);
                h_priv[q][l32] = fast_tanh(s + bs_o);
            }
            // next phase-A read of h_priv[q] is same-wave lgkmcnt-ordered;
            // cross-wave part WAR handled by ping-pong.
        }
    }

    // ---- publish final h, then fused MLP head ----
    if (owner) h_full[o] = h_priv[q][l32];
    bar_lds();

    if (tid < 128) out[1024 + b * 128 + tid] = h_full[tid];

    {
        float acc = b1[tid];
        const float4* wrow = (const float4*)(W1 + (size_t)tid * 128);
#pragma unroll
        for (int k4 = 0; k4 < 32; ++k4) {
            float4 wv = wrow[k4];
            acc += wv.x * h_full[k4 * 4 + 0] + wv.y * h_full[k4 * 4 + 1]
                 + wv.z * h_full[k4 * 4 + 2] + wv.w * h_full[k4 * 4 + 3];
        }
        hid[tid] = fmaxf(acc, 0.f);
    }
    __syncthreads();

    float s = 0.f;
#pragma unroll
    for (int qq = 0; qq < 4; ++qq)
        s += hid[qq * 64 + lane] * W2[q * 256 + qq * 64 + lane];
#pragma unroll
    for (int off = 32; off > 0; off >>= 1) s += __shfl_down(s, off);
    if (lane == 0) out[b * 4 + q] = s + b2[q];
}

// ---------------------------------------------------------------------------
extern "C" void kernel_launch(void* const* d_in, const int* in_sizes, int n_in,
                              void* d_out, int out_size, void* d_ws, size_t ws_size,
                              hipStream_t stream)
{
    const int*   x   = (const int*)d_in[0];
    const float* h0  = (const float*)d_in[1];
    const float* emb = (const float*)d_in[2];
    const float* Wih = (const float*)d_in[3];
    const float* Whh = (const float*)d_in[4];
    const float* bih = (const float*)d_in[5];
    const float* bhh = (const float*)d_in[6];
    const float* W1  = (const float*)d_in[7];
    const float* b1  = (const float*)d_in[8];
    const float* W2  = (const float*)d_in[9];
    const float* b2  = (const float*)d_in[10];
    float* out = (float*)d_out;

    rnn_fused<<<BB, 256, 0, stream>>>(x, emb, Wih, Whh, bih, bhh, h0,
                                      W1, b1, W2, b2, out);
}